// Round 4
// baseline (847.051 us; speedup 1.0000x reference)
//
#include <hip/hip_runtime.h>

// Swin windowed MHA, fully fused, all-MFMA (split-bf16 3-term Markidis, err ~2^-16).
// B=8192 windows, L=49, C=128, H=4, d=32. 512 thr (8 waves) per window, 150KB LDS.
// Phase 1: qkv GEMM — A(x) direct-global + in-reg split; B(W) pre-split in d_ws
//          (fragment-major, coalesced b128) or fallback in-reg split from fp32.
// Phase 2: QK^T = mfma(K,Q) -> S[l][m] (XOR16-swizzled LDS); lane-local softmax;
//          P split-bf16 (XOR8) overlays dead q/k; PV = mfma(V^T,P); deferred 1/sum.
// Phase 3: proj GEMM from Os (LDS) with direct-global pre-split B.

namespace {

constexpr float kScale = 0.17677669529663687f;  // 32^-0.5
constexpr int kLdsBytes = 153600;
// LDS byte map:
//   0      qh[64][136]us   (17408)   | P_h overlay [4][64][128B] (0..32768)
//   17408  ql[64][136]us             |
//   34816  kh[64][136]us             | P_l overlay (32768..65536)
//   52224  kl[64][136]us             |
//   69632  vT_h[128][128B] XOR8 (16384)
//   86016  vT_l[128][128B] XOR8
//   102400 S[4][49][256B] XOR16 (50176) | Os_h@102400 [64][136]us, Os_l@119808
//   152576 rs[4][64] f32 (1024)  -> total 153600

typedef short short8 __attribute__((ext_vector_type(8)));   // 8 bf16, MFMA A/B frag
typedef float f32x4 __attribute__((ext_vector_type(4)));    // MFMA C/D frag
typedef float f4u __attribute__((ext_vector_type(4), aligned(4)));  // unaligned-safe float4
typedef unsigned short us4 __attribute__((ext_vector_type(4)));

__device__ inline unsigned short f2bf(float f) {
  union { float f; unsigned u; } c; c.f = f;
  return (unsigned short)((c.u + 0x7fffu + ((c.u >> 16) & 1u)) >> 16);  // RNE
}
__device__ inline float bf2f(unsigned short h) {
  union { unsigned u; float f; } c; c.u = (unsigned)h << 16; return c.f;
}
__device__ inline void split8(const float* v, short8& h, short8& l) {
#pragma unroll
  for (int j = 0; j < 8; ++j) {
    unsigned short hu = f2bf(v[j]);
    h[j] = (short)hu;
    l[j] = (short)f2bf(v[j] - bf2f(hu));
  }
}

// B-fragment: pre-split fragment-major ws (coalesced: lane lam reads 16B at g*8)
// or fallback: fp32 weight row + in-register split.
template <bool PRE>
__device__ inline void load_bfrag(const unsigned short* __restrict__ wsH,
                                  const unsigned short* __restrict__ wsL,
                                  const float* __restrict__ wraw,
                                  int rb, int kk, int lam, int row, int c0,
                                  short8& bh, short8& bl) {
  if constexpr (PRE) {
    const int off = rb * 2048 + kk * 512 + lam * 8;
    bh = *(const short8*)(wsH + off);
    bl = *(const short8*)(wsL + off);
  } else {
    const float* p = wraw + row * 128 + c0;
    float4 u0 = *(const float4*)p;
    float4 u1 = *(const float4*)(p + 4);
    float v[8] = {u0.x, u0.y, u0.z, u0.w, u1.x, u1.y, u1.z, u1.w};
    split8(v, bh, bl);
  }
}

// One-shot weight pre-split into fragment-major layout.
// group g -> (rb=g>>8, kk=(g&255)>>6, lam=g&63); element (rb*16+fr, kk*32+fq*8+j)
__global__ void presplit_weights(const float* __restrict__ qkv_w,
                                 const float* __restrict__ proj_w,
                                 unsigned short* __restrict__ ws) {
  int g = blockIdx.x * 256 + threadIdx.x;  // 0..8191
  const float* src; unsigned short *dh, *dl; int gl;
  if (g < 6144) { src = qkv_w; dh = ws;         dl = ws + 49152;  gl = g; }
  else          { src = proj_w; dh = ws + 98304; dl = ws + 114688; gl = g - 6144; }
  const int rb = gl >> 8, rem = gl & 255;
  const int kk = rem >> 6, lam = rem & 63, fr = lam & 15, fq = lam >> 4;
  const float* p = src + (rb * 16 + fr) * 128 + kk * 32 + fq * 8;
  float4 u0 = *(const float4*)p, u1 = *(const float4*)(p + 4);
  float v[8] = {u0.x, u0.y, u0.z, u0.w, u1.x, u1.y, u1.z, u1.w};
  short8 hh, ll;
  split8(v, hh, ll);
  *(short8*)(dh + gl * 8) = hh;
  *(short8*)(dl + gl * 8) = ll;
}

template <bool PRE>
__global__ __launch_bounds__(512, 1) void swin_fused(
    const float* __restrict__ x, const float* __restrict__ mask,
    const float* __restrict__ qkv_w, const float* __restrict__ qkv_b,
    const float* __restrict__ bias, const float* __restrict__ proj_w,
    const float* __restrict__ proj_b, float* __restrict__ out,
    const unsigned short* __restrict__ wsp) {
  extern __shared__ char lds[];
  unsigned short* qhs = (unsigned short*)(lds);
  unsigned short* qls = (unsigned short*)(lds + 17408);
  unsigned short* khs = (unsigned short*)(lds + 34816);
  unsigned short* kls = (unsigned short*)(lds + 52224);
  char* vthB = lds + 69632;
  char* vtlB = lds + 86016;
  unsigned short* Osh = (unsigned short*)(lds + 102400);
  unsigned short* Osl = (unsigned short*)(lds + 119808);
  float* rsb = (float*)(lds + 152576);

  const int tid = threadIdx.x;
  const int b = blockIdx.x;
  const int lam = tid & 63;
  const int wv = tid >> 6;   // 0..7
  const int fr = lam & 15;
  const int fq = lam >> 4;

  // ================= Phase 1: qkv = x @ qkv_w^T + b =================
  // A-frags: x direct from global (rows >=49 clamped to 48 -> finite pad), split.
  short8 axh[4][4], axl[4][4];  // [mt][kk]
  {
    const float* xb = x + (size_t)b * (49 * 128);
#pragma unroll
    for (int mt = 0; mt < 4; ++mt) {
      int row = mt * 16 + fr; row = row < 49 ? row : 48;
#pragma unroll
      for (int kk = 0; kk < 4; ++kk) {
        const float* p = xb + row * 128 + kk * 32 + fq * 8;
        float4 u0 = *(const float4*)p, u1 = *(const float4*)(p + 4);
        float v[8] = {u0.x, u0.y, u0.z, u0.w, u1.x, u1.y, u1.z, u1.w};
        split8(v, axh[mt][kk], axl[mt][kk]);
      }
    }
  }
#pragma unroll
  for (int t = 0; t < 3; ++t) {  // t: 0=q, 1=k, 2=v (128 cols each; wave owns 16)
    short8 bh[4], bl[4];
#pragma unroll
    for (int kk = 0; kk < 4; ++kk)
      load_bfrag<PRE>(wsp, wsp + 49152, qkv_w, t * 8 + wv, kk, lam,
                      t * 128 + wv * 16 + fr, kk * 32 + fq * 8, bh[kk], bl[kk]);
    f32x4 acc[4];
#pragma unroll
    for (int mt = 0; mt < 4; ++mt) acc[mt] = (f32x4){0.f, 0.f, 0.f, 0.f};
#pragma unroll
    for (int kk = 0; kk < 4; ++kk) {
#pragma unroll
      for (int mt = 0; mt < 4; ++mt)
        acc[mt] = __builtin_amdgcn_mfma_f32_16x16x32_bf16(axh[mt][kk], bh[kk], acc[mt], 0, 0, 0);
#pragma unroll
      for (int mt = 0; mt < 4; ++mt)
        acc[mt] = __builtin_amdgcn_mfma_f32_16x16x32_bf16(axh[mt][kk], bl[kk], acc[mt], 0, 0, 0);
#pragma unroll
      for (int mt = 0; mt < 4; ++mt)
        acc[mt] = __builtin_amdgcn_mfma_f32_16x16x32_bf16(axl[mt][kk], bh[kk], acc[mt], 0, 0, 0);
    }
    const float bj = qkv_b[t * 128 + wv * 16 + fr];
    if (t == 0) {  // q scaled -> qh/ql [l][c], scalar b16 (D: col=fr, row=fq*4+r)
#pragma unroll
      for (int mt = 0; mt < 4; ++mt)
#pragma unroll
        for (int r = 0; r < 4; ++r) {
          const int row = mt * 16 + fq * 4 + r;
          if (row < 49) {
            const float val = (acc[mt][r] + bj) * kScale;
            const int idx = row * 136 + wv * 16 + fr;
            const unsigned short hu = f2bf(val);
            qhs[idx] = hu;
            qls[idx] = f2bf(val - bf2f(hu));
          }
        }
    } else if (t == 1) {  // k -> kh/kl
#pragma unroll
      for (int mt = 0; mt < 4; ++mt)
#pragma unroll
        for (int r = 0; r < 4; ++r) {
          const int row = mt * 16 + fq * 4 + r;
          if (row < 49) {
            const float val = acc[mt][r] + bj;
            const int idx = row * 136 + wv * 16 + fr;
            const unsigned short hu = f2bf(val);
            khs[idx] = hu;
            kls[idx] = f2bf(val - bf2f(hu));
          }
        }
    } else {  // v -> vT[d-channel][m] XOR8, packed b64; pad cols 49..63 = finite dup
      const int jc = wv * 16 + fr;
      const int vswz = (jc & 7) << 4;
#pragma unroll
      for (int mt = 0; mt < 4; ++mt) {
        us4 hh, ll;
#pragma unroll
        for (int r = 0; r < 4; ++r) {
          const float val = acc[mt][r] + bj;
          const unsigned short hu = f2bf(val);
          hh[r] = hu;
          ll[r] = f2bf(val - bf2f(hu));
        }
        const int l0 = mt * 16 + fq * 4;
        *(us4*)(vthB + jc * 128 + ((l0 * 2) ^ vswz)) = hh;
        *(us4*)(vtlB + jc * 128 + ((l0 * 2) ^ vswz)) = ll;
      }
    }
  }
  __syncthreads();  // B_12: q/k/vT visible

  // ================= Phase 2: attention. wave = (head, l-half) =================
  const int h = wv >> 1, half = wv & 1;
  {  // ---- QK^T: S = mfma(A=K, B=Q) -> D[m][l] ----
    short8 kfh[4], kfl[4], qfh[2], qfl[2];
#pragma unroll
    for (int tm = 0; tm < 4; ++tm) {
      const int off = (tm * 16 + fr) * 136 + h * 32 + fq * 8;
      kfh[tm] = *(const short8*)(khs + off);
      kfl[tm] = *(const short8*)(kls + off);
    }
#pragma unroll
    for (int t2 = 0; t2 < 2; ++t2) {
      const int off = ((half * 2 + t2) * 16 + fr) * 136 + h * 32 + fq * 8;
      qfh[t2] = *(const short8*)(qhs + off);
      qfl[t2] = *(const short8*)(qls + off);
    }
    f32x4 sa[4][2];
#pragma unroll
    for (int tm = 0; tm < 4; ++tm)
#pragma unroll
      for (int t2 = 0; t2 < 2; ++t2) sa[tm][t2] = (f32x4){0.f, 0.f, 0.f, 0.f};
#pragma unroll
    for (int tm = 0; tm < 4; ++tm)
#pragma unroll
      for (int t2 = 0; t2 < 2; ++t2)
        sa[tm][t2] = __builtin_amdgcn_mfma_f32_16x16x32_bf16(kfh[tm], qfh[t2], sa[tm][t2], 0, 0, 0);
#pragma unroll
    for (int tm = 0; tm < 4; ++tm)
#pragma unroll
      for (int t2 = 0; t2 < 2; ++t2)
        sa[tm][t2] = __builtin_amdgcn_mfma_f32_16x16x32_bf16(kfh[tm], qfl[t2], sa[tm][t2], 0, 0, 0);
#pragma unroll
    for (int tm = 0; tm < 4; ++tm)
#pragma unroll
      for (int t2 = 0; t2 < 2; ++t2)
        sa[tm][t2] = __builtin_amdgcn_mfma_f32_16x16x32_bf16(kfl[tm], qfh[t2], sa[tm][t2], 0, 0, 0);
    // S[l][m] rows (l<49), b128 along m, XOR16 swizzle. Garbage m>=49 ignored later.
#pragma unroll
    for (int t2 = 0; t2 < 2; ++t2) {
      const int l = (half * 2 + t2) * 16 + fr;  // D col = fr
      if (l < 49) {
        char* srow = lds + 102400 + h * 12544 + l * 256;
        const int swz = (l & 15) << 4;
#pragma unroll
        for (int tm = 0; tm < 4; ++tm)
          *(f32x4*)(srow + (((tm * 16 + fq * 4) * 4) ^ swz)) = sa[tm][t2];
      }
    }
  }
  __syncthreads();  // B1: S done; q/k dead (P may overlay)

  // ---- softmax: lane-local over m; P rows split-bf16, deferred 1/sum ----
  if (lam < 32) {
    const int l = half * 32 + lam;
    float rsv = 0.f;
    char* PhRow = lds + h * 8192 + (size_t)l * 128;
    char* PlRow = lds + 32768 + h * 8192 + (size_t)l * 128;
    const int pswz = (l & 7) << 4;
    if (l < 49) {
      const char* srow = lds + 102400 + h * 12544 + l * 256;
      const int swz = (l & 15) << 4;
      const float* bi = bias + (h * 49 + l) * 49;
      const float* mk = mask + ((size_t)(b & 63) * 49 + l) * 49;
      float s[49];
      float mx = -3.0e38f;
#pragma unroll
      for (int m0 = 0; m0 < 48; m0 += 4) {
        f32x4 sv = *(const f32x4*)(srow + ((m0 * 4) ^ swz));
        f4u bv = *(const f4u*)(bi + m0);
        f4u mv = *(const f4u*)(mk + m0);
#pragma unroll
        for (int j = 0; j < 4; ++j) {
          const float tt = sv[j] + bv[j] + mv[j];
          s[m0 + j] = tt;
          mx = fmaxf(mx, tt);
        }
      }
      {
        const float tt = *(const float*)(srow + (192 ^ swz)) + bi[48] + mk[48];
        s[48] = tt;
        mx = fmaxf(mx, tt);
      }
      float sum = 0.f;
#pragma unroll
      for (int m = 0; m < 49; ++m) { const float e = __expf(s[m] - mx); s[m] = e; sum += e; }
      rsv = 1.f / sum;
#pragma unroll
      for (int m0 = 0; m0 < 64; m0 += 8) {
        short8 hh, ll;
#pragma unroll
        for (int j = 0; j < 8; ++j) {
          const float p = (m0 + j < 49) ? s[(m0 + j < 49) ? m0 + j : 0] : 0.f;
          const unsigned short hu = f2bf(p);
          hh[j] = (short)hu;
          ll[j] = (short)f2bf(p - bf2f(hu));
        }
        *(short8*)(PhRow + ((m0 * 2) ^ pswz)) = hh;
        *(short8*)(PlRow + ((m0 * 2) ^ pswz)) = ll;
      }
    } else {  // pad query rows: zero P, rs=0 -> Os rows 49..63 = 0
      short8 z = {};
#pragma unroll
      for (int m0 = 0; m0 < 64; m0 += 8) {
        *(short8*)(PhRow + ((m0 * 2) ^ pswz)) = z;
        *(short8*)(PlRow + ((m0 * 2) ^ pswz)) = z;
      }
    }
    rsb[h * 64 + l] = rsv;
  }
  __syncthreads();  // B2: P+rs done; S dead (Os may overlay)

  {  // ---- PV: O^T = mfma(A=V^T, B=P) -> D[d][l]; scale by rs; Os[l][c] ----
    short8 vfh[2][2], vfl[2][2], pfh[2][2], pfl[2][2];
#pragma unroll
    for (int dt = 0; dt < 2; ++dt)
#pragma unroll
      for (int kk = 0; kk < 2; ++kk) {
        const int row = h * 32 + dt * 16 + fr;
        const int off = row * 128 + ((kk * 64 + fq * 16) ^ ((row & 7) << 4));
        vfh[dt][kk] = *(const short8*)(vthB + off);
        vfl[dt][kk] = *(const short8*)(vtlB + off);
      }
#pragma unroll
    for (int t2 = 0; t2 < 2; ++t2)
#pragma unroll
      for (int kk = 0; kk < 2; ++kk) {
        const int l = (half * 2 + t2) * 16 + fr;
        const int off = h * 8192 + l * 128 + ((kk * 64 + fq * 16) ^ ((l & 7) << 4));
        pfh[t2][kk] = *(const short8*)(lds + off);
        pfl[t2][kk] = *(const short8*)(lds + 32768 + off);
      }
    f32x4 oa[2][2];
#pragma unroll
    for (int dt = 0; dt < 2; ++dt)
#pragma unroll
      for (int t2 = 0; t2 < 2; ++t2) oa[dt][t2] = (f32x4){0.f, 0.f, 0.f, 0.f};
#pragma unroll
    for (int kk = 0; kk < 2; ++kk) {
#pragma unroll
      for (int dt = 0; dt < 2; ++dt)
#pragma unroll
        for (int t2 = 0; t2 < 2; ++t2)
          oa[dt][t2] = __builtin_amdgcn_mfma_f32_16x16x32_bf16(vfh[dt][kk], pfh[t2][kk], oa[dt][t2], 0, 0, 0);
#pragma unroll
      for (int dt = 0; dt < 2; ++dt)
#pragma unroll
        for (int t2 = 0; t2 < 2; ++t2)
          oa[dt][t2] = __builtin_amdgcn_mfma_f32_16x16x32_bf16(vfh[dt][kk], pfl[t2][kk], oa[dt][t2], 0, 0, 0);
#pragma unroll
      for (int dt = 0; dt < 2; ++dt)
#pragma unroll
        for (int t2 = 0; t2 < 2; ++t2)
          oa[dt][t2] = __builtin_amdgcn_mfma_f32_16x16x32_bf16(vfl[dt][kk], pfh[t2][kk], oa[dt][t2], 0, 0, 0);
    }
#pragma unroll
    for (int t2 = 0; t2 < 2; ++t2) {
      const int l = (half * 2 + t2) * 16 + fr;
      const float rsl = rsb[h * 64 + l];
#pragma unroll
      for (int dt = 0; dt < 2; ++dt) {
        us4 hh, ll;
#pragma unroll
        for (int r = 0; r < 4; ++r) {
          const float val = oa[dt][t2][r] * rsl;
          const unsigned short hu = f2bf(val);
          hh[r] = hu;
          ll[r] = f2bf(val - bf2f(hu));
        }
        const int idx = l * 136 + h * 32 + dt * 16 + fq * 4;
        *(us4*)(&Osh[idx]) = hh;
        *(us4*)(&Osl[idx]) = ll;
      }
    }
  }
  __syncthreads();  // B3: Os done

  // ================= Phase 3: out = Os @ proj_w^T + b =================
  {
    short8 ah[4][4], al[4][4];
#pragma unroll
    for (int mt = 0; mt < 4; ++mt)
#pragma unroll
      for (int kk = 0; kk < 4; ++kk) {
        const int off = (mt * 16 + fr) * 136 + kk * 32 + fq * 8;
        ah[mt][kk] = *(const short8*)(&Osh[off]);
        al[mt][kk] = *(const short8*)(&Osl[off]);
      }
    short8 bh[4], bl[4];
#pragma unroll
    for (int kk = 0; kk < 4; ++kk)
      load_bfrag<PRE>(wsp + 98304, wsp + 114688, proj_w, wv, kk, lam,
                      wv * 16 + fr, kk * 32 + fq * 8, bh[kk], bl[kk]);
    f32x4 acc[4];
#pragma unroll
    for (int mt = 0; mt < 4; ++mt) acc[mt] = (f32x4){0.f, 0.f, 0.f, 0.f};
#pragma unroll
    for (int kk = 0; kk < 4; ++kk) {
#pragma unroll
      for (int mt = 0; mt < 4; ++mt)
        acc[mt] = __builtin_amdgcn_mfma_f32_16x16x32_bf16(ah[mt][kk], bh[kk], acc[mt], 0, 0, 0);
#pragma unroll
      for (int mt = 0; mt < 4; ++mt)
        acc[mt] = __builtin_amdgcn_mfma_f32_16x16x32_bf16(ah[mt][kk], bl[kk], acc[mt], 0, 0, 0);
#pragma unroll
      for (int mt = 0; mt < 4; ++mt)
        acc[mt] = __builtin_amdgcn_mfma_f32_16x16x32_bf16(al[mt][kk], bh[kk], acc[mt], 0, 0, 0);
    }
    const int col = wv * 16 + fr;
    const float bj = proj_b[col];
    float* og = out + (size_t)b * (49 * 128);
#pragma unroll
    for (int mt = 0; mt < 4; ++mt)
#pragma unroll
      for (int r = 0; r < 4; ++r) {
        const int row = mt * 16 + fq * 4 + r;
        if (row < 49) og[row * 128 + col] = acc[mt][r] + bj;
      }
  }
}

}  // namespace

extern "C" void kernel_launch(void* const* d_in, const int* in_sizes, int n_in,
                              void* d_out, int out_size, void* d_ws, size_t ws_size,
                              hipStream_t stream) {
  (void)in_sizes; (void)n_in; (void)out_size;
  const float* x      = (const float*)d_in[0];
  const float* mask   = (const float*)d_in[1];
  const float* qkv_w  = (const float*)d_in[2];
  const float* qkv_b  = (const float*)d_in[3];
  const float* bias   = (const float*)d_in[4];
  const float* proj_w = (const float*)d_in[5];
  const float* proj_b = (const float*)d_in[6];
  float* out = (float*)d_out;

  const bool pre = (d_ws != nullptr) && (ws_size >= 262144);
  hipFuncSetAttribute(reinterpret_cast<const void*>(&swin_fused<true>),
                      hipFuncAttributeMaxDynamicSharedMemorySize, kLdsBytes);
  hipFuncSetAttribute(reinterpret_cast<const void*>(&swin_fused<false>),
                      hipFuncAttributeMaxDynamicSharedMemorySize, kLdsBytes);
  if (pre) {
    presplit_weights<<<32, 256, 0, stream>>>(qkv_w, proj_w, (unsigned short*)d_ws);
    swin_fused<true><<<8192, 512, kLdsBytes, stream>>>(
        x, mask, qkv_w, qkv_b, bias, proj_w, proj_b, out, (const unsigned short*)d_ws);
  } else {
    swin_fused<false><<<8192, 512, kLdsBytes, stream>>>(
        x, mask, qkv_w, qkv_b, bias, proj_w, proj_b, out, nullptr);
  }
}

// Round 5
// 502.141 us; speedup vs baseline: 1.6869x; 1.6869x over previous
//
#include <hip/hip_runtime.h>

// Swin windowed MHA, fully fused, single-bf16 MFMA everywhere (fp32 accum).
// B=8192 windows, L=49, C=128, H=4, d=32. 512 thr (8 waves)/window.
// 67 KB LDS via overlays -> 2 blocks/CU (16 waves). Weights pre-converted to
// fragment-major bf16 in d_ws (fallback: in-kernel convert from fp32).

namespace {

constexpr float kScale = 0.17677669529663687f;  // 32^-0.5
constexpr int kLds = 68608;
// LDS byte map (overlays):
//   0     vT[128][128B] bf16, XOR8 by d-row      | Os[64][136]us overlay after PV
//   16384 xs[64][136]us  (x bf16)                | S[4][49][256B] f32 overlay,
//   33792 qs[64][136]us  (q bf16, pre-scaled)    |   XOR16 by l; P overlays first
//   51200 ks[64][136]us  (k bf16)                |   128B of each S row (XOR8)
//   total 68608 -> 2 blocks/CU (137216 <= 163840)

typedef short short8 __attribute__((ext_vector_type(8)));   // 8 bf16 MFMA frag
typedef float f32x4 __attribute__((ext_vector_type(4)));    // MFMA C/D frag
typedef float f4u __attribute__((ext_vector_type(4), aligned(4)));  // dword-aligned f32x4
typedef unsigned short us4 __attribute__((ext_vector_type(4)));

__device__ inline unsigned short f2bf(float f) {  // RNE via HW cvt
  __bf16 h = (__bf16)f;
  union { __bf16 b; unsigned short u; } c; c.b = h;
  return c.u;
}

// Weights -> fragment-major bf16: group g=(rb,kk,lam) holds 8 elems
// (rb*16+fr, kk*32+fq*8+j). qkv: rb 0..23 (6144 groups); proj: rb 0..7 (2048).
__global__ void prep_weights(const float* __restrict__ qkv_w,
                             const float* __restrict__ proj_w,
                             unsigned short* __restrict__ ws) {
  const int g = blockIdx.x * 256 + threadIdx.x;  // 0..8191
  const float* src; unsigned short* dst; int gl;
  if (g < 6144) { src = qkv_w;  dst = ws;         gl = g; }
  else          { src = proj_w; dst = ws + 49152; gl = g - 6144; }
  const int rb = gl >> 8, rem = gl & 255, kk = rem >> 6, lam = rem & 63;
  const int fr = lam & 15, fq = lam >> 4;
  const float* p = src + (size_t)(rb * 16 + fr) * 128 + kk * 32 + fq * 8;
  float4 u0 = *(const float4*)p, u1 = *(const float4*)(p + 4);
  short8 o;
  o[0] = (short)f2bf(u0.x); o[1] = (short)f2bf(u0.y);
  o[2] = (short)f2bf(u0.z); o[3] = (short)f2bf(u0.w);
  o[4] = (short)f2bf(u1.x); o[5] = (short)f2bf(u1.y);
  o[6] = (short)f2bf(u1.z); o[7] = (short)f2bf(u1.w);
  *(short8*)(dst + (size_t)gl * 8) = o;
}

template <bool PRE>
__global__ __launch_bounds__(512, 4) void swin_fused(
    const float* __restrict__ x, const float* __restrict__ mask,
    const float* __restrict__ qkv_w, const float* __restrict__ qkv_b,
    const float* __restrict__ bias, const float* __restrict__ proj_w,
    const float* __restrict__ proj_b, float* __restrict__ out,
    const unsigned short* __restrict__ wsp) {
  extern __shared__ char lds[];
  char* vtB = lds;                                      // vT
  unsigned short* xs = (unsigned short*)(lds + 16384);  // [64][136]
  unsigned short* qs = (unsigned short*)(lds + 33792);
  unsigned short* ks = (unsigned short*)(lds + 51200);
  char* SB = lds + 16384;                               // S overlay (after B2.5)
  unsigned short* Os = (unsigned short*)lds;            // Os overlay (after B5)

  const int tid = threadIdx.x;
  const int b = blockIdx.x;
  const int lam = tid & 63;
  const int wv = tid >> 6;   // 0..7
  const int fr = lam & 15;
  const int fq = lam >> 4;

  // ---- P0: stage x -> xs bf16; zero pad rows 49..63 ----
  {
    const float4* xg = (const float4*)(x + (size_t)b * 6272);
    for (int idx = tid; idx < 1568; idx += 512) {
      const int r = idx >> 5, c4 = idx & 31;
      const float4 v = xg[idx];
      us4 h4 = {f2bf(v.x), f2bf(v.y), f2bf(v.z), f2bf(v.w)};
      *(us4*)(&xs[r * 136 + c4 * 4]) = h4;
    }
    const us4 z = {0, 0, 0, 0};
    for (int idx = tid; idx < 480; idx += 512) {
      const int r = 49 + (idx >> 5), c4 = idx & 31;
      *(us4*)(&xs[r * 136 + c4 * 4]) = z;
    }
  }
  __syncthreads();  // B1

  // ---- P1: qkv = x @ qkv_w^T + b; wave wv owns 16 output cols per t ----
  short8 ax[4][4];
#pragma unroll
  for (int mt = 0; mt < 4; ++mt)
#pragma unroll
    for (int kk = 0; kk < 4; ++kk)
      ax[mt][kk] = *(const short8*)(&xs[(mt * 16 + fr) * 136 + kk * 32 + fq * 8]);

#pragma unroll
  for (int t = 0; t < 3; ++t) {  // 0=q 1=k 2=v
    short8 bw[4];
    if constexpr (PRE) {
#pragma unroll
      for (int kk = 0; kk < 4; ++kk)
        bw[kk] = *(const short8*)(wsp + (size_t)(t * 8 + wv) * 2048 + kk * 512 + lam * 8);
    } else {
#pragma unroll
      for (int kk = 0; kk < 4; ++kk) {
        const float* p = qkv_w + (size_t)(t * 128 + wv * 16 + fr) * 128 + kk * 32 + fq * 8;
        float4 u0 = *(const float4*)p, u1 = *(const float4*)(p + 4);
        short8 o;
        o[0] = (short)f2bf(u0.x); o[1] = (short)f2bf(u0.y);
        o[2] = (short)f2bf(u0.z); o[3] = (short)f2bf(u0.w);
        o[4] = (short)f2bf(u1.x); o[5] = (short)f2bf(u1.y);
        o[6] = (short)f2bf(u1.z); o[7] = (short)f2bf(u1.w);
        bw[kk] = o;
      }
    }
    f32x4 acc[4];
#pragma unroll
    for (int mt = 0; mt < 4; ++mt) acc[mt] = (f32x4){0.f, 0.f, 0.f, 0.f};
#pragma unroll
    for (int kk = 0; kk < 4; ++kk)
#pragma unroll
      for (int mt = 0; mt < 4; ++mt)
        acc[mt] = __builtin_amdgcn_mfma_f32_16x16x32_bf16(ax[mt][kk], bw[kk], acc[mt], 0, 0, 0);

    const float bj = qkv_b[t * 128 + wv * 16 + fr];
    if (t == 0) {  // q (scaled); D: col=fr, row=fq*4+r
#pragma unroll
      for (int mt = 0; mt < 4; ++mt)
#pragma unroll
        for (int r = 0; r < 4; ++r) {
          const int row = mt * 16 + fq * 4 + r;
          if (row < 49) qs[row * 136 + wv * 16 + fr] = f2bf((acc[mt][r] + bj) * kScale);
        }
    } else if (t == 1) {  // k
#pragma unroll
      for (int mt = 0; mt < 4; ++mt)
#pragma unroll
        for (int r = 0; r < 4; ++r) {
          const int row = mt * 16 + fq * 4 + r;
          if (row < 49) ks[row * 136 + wv * 16 + fr] = f2bf(acc[mt][r] + bj);
        }
    } else {  // v -> vT[d-chan][m] XOR8 (pad m rows finite; killed by P=0)
      const int jc = wv * 16 + fr;
      const int vsw = (jc & 7) << 4;
#pragma unroll
      for (int mt = 0; mt < 4; ++mt) {
        us4 h4;
#pragma unroll
        for (int r = 0; r < 4; ++r) h4[r] = f2bf(acc[mt][r] + bj);
        const int m0 = mt * 16 + fq * 4;
        *(us4*)(vtB + jc * 128 + ((m0 * 2) ^ vsw)) = h4;
      }
    }
  }
  __syncthreads();  // B2: q/k/vT visible

  // ---- P2a: QK^T = mfma(K,Q) -> S[l][m]; wave = (head h, l-half) ----
  const int h = wv >> 1, half = wv & 1;
  short8 kf[4], qf[2];
#pragma unroll
  for (int tm = 0; tm < 4; ++tm)
    kf[tm] = *(const short8*)(&ks[(tm * 16 + fr) * 136 + h * 32 + fq * 8]);
#pragma unroll
  for (int t2 = 0; t2 < 2; ++t2)
    qf[t2] = *(const short8*)(&qs[((half * 2 + t2) * 16 + fr) * 136 + h * 32 + fq * 8]);
  __syncthreads();  // B2.5: frags in regs; S may now overwrite xs/qs/ks

  {
    f32x4 sa[4][2];
#pragma unroll
    for (int tm = 0; tm < 4; ++tm)
#pragma unroll
      for (int t2 = 0; t2 < 2; ++t2)
        sa[tm][t2] = __builtin_amdgcn_mfma_f32_16x16x32_bf16(
            kf[tm], qf[t2], (f32x4){0.f, 0.f, 0.f, 0.f}, 0, 0, 0);
#pragma unroll
    for (int t2 = 0; t2 < 2; ++t2) {
      const int l = (half * 2 + t2) * 16 + fr;  // D col = fr
      if (l < 49) {
        char* srow = SB + h * 12544 + l * 256;
        const int sw = (l & 15) << 4;
#pragma unroll
        for (int tm = 0; tm < 4; ++tm)
          *(f32x4*)(srow + (((tm * 16 + fq * 4) * 4) ^ sw)) = sa[tm][t2];
      }
    }
  }
  __syncthreads();  // B3: S done

  // ---- P2b: softmax per l-row (lanes 0..31 of each wave); P overlays S row ----
  float rsv = 0.f;
  if (lam < 32) {
    const int l = half * 32 + lam;
    if (l < 49) {
      char* srow = SB + h * 12544 + l * 256;
      const int sw = (l & 15) << 4;
      const float* bi = bias + ((size_t)h * 49 + l) * 49;
      const float* mk = mask + ((size_t)(b & 63) * 49 + l) * 49;
      float s[49];
      float mx = -3.0e38f;
#pragma unroll
      for (int m0 = 0; m0 < 48; m0 += 4) {
        f32x4 sv = *(const f32x4*)(srow + ((m0 * 4) ^ sw));
        f4u bv = *(const f4u*)(bi + m0);
        f4u mv = *(const f4u*)(mk + m0);
#pragma unroll
        for (int j = 0; j < 4; ++j) {
          const float t = sv[j] + bv[j] + mv[j];
          s[m0 + j] = t;
          mx = fmaxf(mx, t);
        }
      }
      {
        const float t = *(const float*)(srow + (192 ^ sw)) + bi[48] + mk[48];
        s[48] = t;
        mx = fmaxf(mx, t);
      }
      float sum = 0.f;
#pragma unroll
      for (int m = 0; m < 49; ++m) { const float e = __expf(s[m] - mx); s[m] = e; sum += e; }
      rsv = 1.f / sum;
      const int pw = (l & 7) << 4;  // P bf16 in first 128B of this S row
#pragma unroll
      for (int m0 = 0; m0 < 64; m0 += 8) {
        short8 ph;
#pragma unroll
        for (int j = 0; j < 8; ++j)
          ph[j] = (short)f2bf((m0 + j < 49) ? s[m0 + j] : 0.f);
        *(short8*)(srow + ((m0 * 2) ^ pw)) = ph;
      }
    }
  }
  __syncthreads();  // B4: P + rsv ready

  // ---- P2c: PV: O^T = mfma(V^T, P) -> D[d][l]; rs via shfl ----
  f32x4 oa[2][2];
  float rsl[2];
  {
    short8 vf[2][2], pf[2][2];
#pragma unroll
    for (int dt = 0; dt < 2; ++dt)
#pragma unroll
      for (int kk = 0; kk < 2; ++kk) {
        const int dv = h * 32 + dt * 16 + fr;
        vf[dt][kk] = *(const short8*)(vtB + dv * 128 + ((kk * 64 + fq * 16) ^ ((dv & 7) << 4)));
      }
    const short8 z8 = {};
#pragma unroll
    for (int t2 = 0; t2 < 2; ++t2)
#pragma unroll
      for (int kk = 0; kk < 2; ++kk) {
        const int l = (half * 2 + t2) * 16 + fr;
        pf[t2][kk] = z8;
        if (l < 49)
          pf[t2][kk] = *(const short8*)(SB + h * 12544 + l * 256 +
                                        ((kk * 64 + fq * 16) ^ ((l & 7) << 4)));
      }
#pragma unroll
    for (int dt = 0; dt < 2; ++dt)
#pragma unroll
      for (int t2 = 0; t2 < 2; ++t2) oa[dt][t2] = (f32x4){0.f, 0.f, 0.f, 0.f};
#pragma unroll
    for (int kk = 0; kk < 2; ++kk)
#pragma unroll
      for (int dt = 0; dt < 2; ++dt)
#pragma unroll
        for (int t2 = 0; t2 < 2; ++t2)
          oa[dt][t2] = __builtin_amdgcn_mfma_f32_16x16x32_bf16(vf[dt][kk], pf[t2][kk],
                                                               oa[dt][t2], 0, 0, 0);
#pragma unroll
    for (int t2 = 0; t2 < 2; ++t2) rsl[t2] = __shfl(rsv, t2 * 16 + fr, 64);
  }
  __syncthreads();  // B5: all vT/P reads done -> Os overlay safe

  // ---- P2d: Os[l][c] bf16 (pad l rows = 0 via rsl=0) ----
#pragma unroll
  for (int t2 = 0; t2 < 2; ++t2) {
    const int l = (half * 2 + t2) * 16 + fr;
#pragma unroll
    for (int dt = 0; dt < 2; ++dt) {
      us4 h4;
#pragma unroll
      for (int r = 0; r < 4; ++r) h4[r] = f2bf(oa[dt][t2][r] * rsl[t2]);
      *(us4*)(&Os[l * 136 + h * 32 + dt * 16 + fq * 4]) = h4;
    }
  }
  __syncthreads();  // B6: Os visible

  // ---- P3: out = Os @ proj_w^T + b ----
  {
    short8 ao[4][4];
#pragma unroll
    for (int mt = 0; mt < 4; ++mt)
#pragma unroll
      for (int kk = 0; kk < 4; ++kk)
        ao[mt][kk] = *(const short8*)(&Os[(mt * 16 + fr) * 136 + kk * 32 + fq * 8]);
    short8 bw[4];
    if constexpr (PRE) {
#pragma unroll
      for (int kk = 0; kk < 4; ++kk)
        bw[kk] = *(const short8*)(wsp + 49152 + (size_t)wv * 2048 + kk * 512 + lam * 8);
    } else {
#pragma unroll
      for (int kk = 0; kk < 4; ++kk) {
        const float* p = proj_w + (size_t)(wv * 16 + fr) * 128 + kk * 32 + fq * 8;
        float4 u0 = *(const float4*)p, u1 = *(const float4*)(p + 4);
        short8 o;
        o[0] = (short)f2bf(u0.x); o[1] = (short)f2bf(u0.y);
        o[2] = (short)f2bf(u0.z); o[3] = (short)f2bf(u0.w);
        o[4] = (short)f2bf(u1.x); o[5] = (short)f2bf(u1.y);
        o[6] = (short)f2bf(u1.z); o[7] = (short)f2bf(u1.w);
        bw[kk] = o;
      }
    }
    f32x4 acc[4];
#pragma unroll
    for (int mt = 0; mt < 4; ++mt) acc[mt] = (f32x4){0.f, 0.f, 0.f, 0.f};
#pragma unroll
    for (int kk = 0; kk < 4; ++kk)
#pragma unroll
      for (int mt = 0; mt < 4; ++mt)
        acc[mt] = __builtin_amdgcn_mfma_f32_16x16x32_bf16(ao[mt][kk], bw[kk], acc[mt], 0, 0, 0);

    const int col = wv * 16 + fr;
    const float bj = proj_b[col];
    float* og = out + (size_t)b * 6272;
#pragma unroll
    for (int mt = 0; mt < 4; ++mt)
#pragma unroll
      for (int r = 0; r < 4; ++r) {
        const int row = mt * 16 + fq * 4 + r;
        if (row < 49) og[row * 128 + col] = acc[mt][r] + bj;
      }
  }
}

}  // namespace

extern "C" void kernel_launch(void* const* d_in, const int* in_sizes, int n_in,
                              void* d_out, int out_size, void* d_ws, size_t ws_size,
                              hipStream_t stream) {
  (void)in_sizes; (void)n_in; (void)out_size;
  const float* x      = (const float*)d_in[0];
  const float* mask   = (const float*)d_in[1];
  const float* qkv_w  = (const float*)d_in[2];
  const float* qkv_b  = (const float*)d_in[3];
  const float* bias   = (const float*)d_in[4];
  const float* proj_w = (const float*)d_in[5];
  const float* proj_b = (const float*)d_in[6];
  float* out = (float*)d_out;

  const bool pre = (d_ws != nullptr) && (ws_size >= 131072);
  hipFuncSetAttribute(reinterpret_cast<const void*>(&swin_fused<true>),
                      hipFuncAttributeMaxDynamicSharedMemorySize, kLds);
  hipFuncSetAttribute(reinterpret_cast<const void*>(&swin_fused<false>),
                      hipFuncAttributeMaxDynamicSharedMemorySize, kLds);
  if (pre) {
    prep_weights<<<32, 256, 0, stream>>>(qkv_w, proj_w, (unsigned short*)d_ws);
    swin_fused<true><<<8192, 512, kLds, stream>>>(x, mask, qkv_w, qkv_b, bias,
                                                  proj_w, proj_b, out,
                                                  (const unsigned short*)d_ws);
  } else {
    swin_fused<false><<<8192, 512, kLds, stream>>>(x, mask, qkv_w, qkv_b, bias,
                                                   proj_w, proj_b, out, nullptr);
  }
}